// Round 1
// baseline (1285.008 us; speedup 1.0000x reference)
//
#include <hip/hip_runtime.h>

#define H_DIM 1024
#define HEADS 16
#define HD 64
#define BATCH 4
#define SEQ 2048
#define M_ROWS (BATCH*SEQ)   // 8192

constexpr int BM = 64, BN = 64, BK = 16;

enum { EPI_NONE = 0, EPI_PHI = 1 };

// C[m,n] = sum_k A[m,k] * W[n,k] + bias[n], optional phi epilogue.
// A: [M,K] row-major, W: [N,K] row-major (torch Linear convention).
template<int EPI>
__global__ __launch_bounds__(256) void gemm_bt(const float* __restrict__ A,
                                               const float* __restrict__ W,
                                               const float* __restrict__ bias,
                                               float* __restrict__ C,
                                               int M, int N, int K)
{
    __shared__ float Ast[BK][BM];   // transposed: [k][m], rows are 256B -> float4 reads ok
    __shared__ float Bst[BK][BN];

    const int tid = threadIdx.x;
    const int bm = blockIdx.y * BM;
    const int bn = blockIdx.x * BN;
    const int tx = tid & 15;        // 16 cols of threads
    const int ty = tid >> 4;        // 16 rows of threads
    const int lrow = tid >> 2;      // 0..63 : tile row to load
    const int lcol = (tid & 3) << 2;// 0,4,8,12 : k offset (float4)

    float acc[4][4] = {};

    const float* Aptr = A + (size_t)(bm + lrow) * K + lcol;
    const float* Wptr = W + (size_t)(bn + lrow) * K + lcol;

    for (int k0 = 0; k0 < K; k0 += BK) {
        float4 a4 = *(const float4*)(Aptr + k0);
        float4 b4 = *(const float4*)(Wptr + k0);
        __syncthreads();   // previous iteration's LDS reads complete
        Ast[lcol+0][lrow] = a4.x; Ast[lcol+1][lrow] = a4.y;
        Ast[lcol+2][lrow] = a4.z; Ast[lcol+3][lrow] = a4.w;
        Bst[lcol+0][lrow] = b4.x; Bst[lcol+1][lrow] = b4.y;
        Bst[lcol+2][lrow] = b4.z; Bst[lcol+3][lrow] = b4.w;
        __syncthreads();
        #pragma unroll
        for (int k = 0; k < BK; ++k) {
            float4 av = *(const float4*)&Ast[k][ty << 2];
            float4 bv = *(const float4*)&Bst[k][tx << 2];
            float ar[4] = {av.x, av.y, av.z, av.w};
            float br[4] = {bv.x, bv.y, bv.z, bv.w};
            #pragma unroll
            for (int i = 0; i < 4; ++i)
                #pragma unroll
                for (int j = 0; j < 4; ++j)
                    acc[i][j] = fmaf(ar[i], br[j], acc[i][j]);
        }
    }

    #pragma unroll
    for (int i = 0; i < 4; ++i) {
        float* orow = C + (size_t)(bm + (ty << 2) + i) * N + bn + (tx << 2);
        float vals[4];
        #pragma unroll
        for (int j = 0; j < 4; ++j) {
            float x = acc[i][j] + bias[bn + (tx << 2) + j];
            if (EPI == EPI_PHI) x = (x > 0.f) ? (x + 1.f) : __expf(x);  // elu(x)+1
            vals[j] = x;
        }
        float4 o = {vals[0], vals[1], vals[2], vals[3]};
        *(float4*)orow = o;
    }
}

// b = sigmoid(beta @ Wb^T + bb): [8192,1024] x [16,1024]^T -> [8192,16]
__global__ __launch_bounds__(256) void proj_b(const float* __restrict__ beta,
                                              const float* __restrict__ Wb,
                                              const float* __restrict__ bbias,
                                              float* __restrict__ bout)
{
    const int n = threadIdx.x & 15;
    const int mloc = threadIdx.x >> 4;
    const int m = blockIdx.x * 16 + mloc;
    const float4* arow = (const float4*)(beta + (size_t)m * H_DIM);
    const float4* wrow = (const float4*)(Wb + (size_t)n * H_DIM);
    float s = 0.f;
    #pragma unroll 4
    for (int k = 0; k < H_DIM / 4; ++k) {
        float4 a = arow[k], w = wrow[k];
        s = fmaf(a.x, w.x, s); s = fmaf(a.y, w.y, s);
        s = fmaf(a.z, w.z, s); s = fmaf(a.w, w.w, s);
    }
    s += bbias[n];
    bout[(size_t)m * HEADS + n] = 1.f / (1.f + __expf(-s));
}

// Diagonal-state delta-rule scan. One block per (batch, head); thread = dim d.
// In-place: reads phi_q, writes y over it.
__global__ __launch_bounds__(64) void scan_kernel(const float* __restrict__ pk_,
                                                  float* __restrict__ pq_,
                                                  const float* __restrict__ v_,
                                                  const float* __restrict__ b_)
{
    const int bb = blockIdx.x >> 4;
    const int h  = blockIdx.x & 15;
    const int d  = threadIdx.x;
    const size_t base = (size_t)bb * SEQ * H_DIM + h * HD + d;
    const float* pkp = pk_ + base;
    float*       pqp = pq_ + base;
    const float* vp  = v_ + base;
    const float* bp  = b_ + (size_t)bb * SEQ * HEADS + h;

    float s = 0.f;
    for (int t = 0; t < SEQ; ++t) {
        float pk = pkp[(size_t)t * H_DIM];
        float pq = pqp[(size_t)t * H_DIM];
        float vv = vp[(size_t)t * H_DIM];
        float bt = bp[(size_t)t * HEADS];
        float bdv = bt * (vv - s * pk);   // b*(v - s*pk)
        s = fmaf(bdv, pk, s);             // s += bdv*pk
        pqp[(size_t)t * H_DIM] = s * pq;  // y = s_new * pq
    }
}

extern "C" void kernel_launch(void* const* d_in, const int* in_sizes, int n_in,
                              void* d_out, int out_size, void* d_ws, size_t ws_size,
                              hipStream_t stream)
{
    const float* query = (const float*)d_in[0];
    const float* key   = (const float*)d_in[1];
    const float* value = (const float*)d_in[2];
    const float* beta  = (const float*)d_in[3];
    const float* Wq    = (const float*)d_in[4];
    const float* bq    = (const float*)d_in[5];
    const float* Wk    = (const float*)d_in[6];
    const float* bk    = (const float*)d_in[7];
    const float* Wv    = (const float*)d_in[8];
    const float* bv    = (const float*)d_in[9];
    const float* Wb    = (const float*)d_in[10];
    const float* bbias = (const float*)d_in[11];
    const float* Wo    = (const float*)d_in[12];
    const float* bo    = (const float*)d_in[13];
    float* out = (float*)d_out;

    float* ws    = (float*)d_ws;
    float* phi_q = ws;                                 // [8192,1024]; becomes ys in-place
    float* phi_k = ws + (size_t)M_ROWS * H_DIM;        // [8192,1024]
    float* vbuf  = ws + 2 * (size_t)M_ROWS * H_DIM;    // [8192,1024]
    float* bbuf  = ws + 3 * (size_t)M_ROWS * H_DIM;    // [8192,16]

    dim3 ggrid(H_DIM / BN, M_ROWS / BM);               // (16, 128)
    gemm_bt<EPI_PHI ><<<ggrid, 256, 0, stream>>>(query, Wq, bq, phi_q, M_ROWS, H_DIM, H_DIM);
    gemm_bt<EPI_PHI ><<<ggrid, 256, 0, stream>>>(key,   Wk, bk, phi_k, M_ROWS, H_DIM, H_DIM);
    gemm_bt<EPI_NONE><<<ggrid, 256, 0, stream>>>(value, Wv, bv, vbuf,  M_ROWS, H_DIM, H_DIM);
    proj_b<<<M_ROWS / 16, 256, 0, stream>>>(beta, Wb, bbias, bbuf);
    scan_kernel<<<BATCH * HEADS, 64, 0, stream>>>(phi_k, phi_q, vbuf, bbuf);
    gemm_bt<EPI_NONE><<<ggrid, 256, 0, stream>>>(phi_q, Wo, bo, out, M_ROWS, H_DIM, H_DIM);
}

// Round 2
// 686.036 us; speedup vs baseline: 1.8731x; 1.8731x over previous
//
#include <hip/hip_runtime.h>
#include <cstdint>
#include <cstddef>

#define H_DIM 1024
#define HEADS 16
#define HD 64
#define BATCH 4
#define SEQ 2048
#define M_ROWS (BATCH*SEQ)   // 8192

typedef __bf16 bf16x8 __attribute__((ext_vector_type(8)));
typedef float floatx4 __attribute__((ext_vector_type(4)));
typedef unsigned short ushortx8 __attribute__((ext_vector_type(8)));

__device__ __forceinline__ unsigned short f2bf(float f) {
    union { float f; uint32_t u; } c; c.f = f;
    uint32_t u = c.u;
    u += 0x7fffu + ((u >> 16) & 1u);     // RNE
    return (unsigned short)(u >> 16);
}
__device__ __forceinline__ float bf2f(unsigned short h) {
    union { uint32_t u; float f; } c; c.u = ((uint32_t)h) << 16;
    return c.f;
}

// async global->LDS, 16B per lane; LDS dest = wave-uniform base + lane*16 (m104/m108)
#define GLD_LDS16(gp, lp) \
    __builtin_amdgcn_global_load_lds((__attribute__((address_space(1))) void*)(gp), \
                                     (__attribute__((address_space(3))) void*)(lp), 16, 0, 0)

// ---------------- elementwise f32 -> bf16 cast (8 elems/thread) ----------------
__global__ __launch_bounds__(256) void cast_bf16(const float* __restrict__ in,
                                                 unsigned short* __restrict__ out)
{
    size_t i = (size_t)blockIdx.x * 256 + threadIdx.x;
    const float4* p = (const float4*)in;
    float4 a = p[i * 2], b = p[i * 2 + 1];
    ushortx8 o;
    o[0] = f2bf(a.x); o[1] = f2bf(a.y); o[2] = f2bf(a.z); o[3] = f2bf(a.w);
    o[4] = f2bf(b.x); o[5] = f2bf(b.y); o[6] = f2bf(b.z); o[7] = f2bf(b.w);
    *(ushortx8*)(out + i * 8) = o;
}

// ---------------- bf16 MFMA GEMM: C[m,n] = sum_k A[m,k]*W[n,k] + bias[n] ------
// m97 structure: 128x128 tile, BK=32, 4 waves x (4x4) 16x16x32 MFMA tiles.
enum { EPI_NONE = 0, EPI_PHI = 1 };

__device__ __forceinline__ void store_out(float* C, size_t idx, float x) { C[idx] = x; }
__device__ __forceinline__ void store_out(unsigned short* C, size_t idx, float x) { C[idx] = f2bf(x); }

template<int EPI, typename OutT>
__global__ __launch_bounds__(256) void gemm_mfma(const unsigned short* __restrict__ A,  // [M,K] bf16
                                                 const unsigned short* __restrict__ W,  // [N,K] bf16
                                                 const float* __restrict__ bias,
                                                 OutT* __restrict__ C,
                                                 int M, int N, int K)
{
    constexpr int TM = 128, TN = 128, TK = 32;
    __shared__ __align__(16) unsigned short Ast[TM * TK];  // row-major [128][32]
    __shared__ __align__(16) unsigned short Bst[TN * TK];

    const int tid  = threadIdx.x;
    const int wave = tid >> 6;
    const int lane = tid & 63;
    const int bm = blockIdx.y * TM;
    const int bn = blockIdx.x * TN;

    // staging: wave covers 16 rows per issue; lane i -> row i>>2, k-chunk (i&3)*8
    const int srow  = wave * 16 + (lane >> 2);
    const int skoff = (lane & 3) * 8;

    const int wm   = (wave & 1) * 64;   // wave's 64x64 quadrant
    const int wn   = (wave >> 1) * 64;
    const int quad = lane >> 4;
    const int l16  = lane & 15;

    floatx4 acc[4][4] = {};

    const unsigned short* Abase = A + (size_t)bm * K;
    const unsigned short* Wbase = W + (size_t)bn * K;

    for (int k0 = 0; k0 < K; k0 += TK) {
        __syncthreads();  // prior iteration's ds_reads complete before overwrite
        GLD_LDS16(Abase + (size_t)srow        * K + k0 + skoff, &Ast[(wave * 16)      * TK]);
        GLD_LDS16(Abase + (size_t)(srow + 64) * K + k0 + skoff, &Ast[(64 + wave * 16) * TK]);
        GLD_LDS16(Wbase + (size_t)srow        * K + k0 + skoff, &Bst[(wave * 16)      * TK]);
        GLD_LDS16(Wbase + (size_t)(srow + 64) * K + k0 + skoff, &Bst[(64 + wave * 16) * TK]);
        __syncthreads();  // drains vmcnt (staging) + lgkm

        bf16x8 af[4], bfr[4];
        #pragma unroll
        for (int i = 0; i < 4; ++i)
            af[i] = *(const bf16x8*)&Ast[(wm + i * 16 + l16) * TK + quad * 8];
        #pragma unroll
        for (int j = 0; j < 4; ++j)
            bfr[j] = *(const bf16x8*)&Bst[(wn + j * 16 + l16) * TK + quad * 8];
        #pragma unroll
        for (int i = 0; i < 4; ++i)
            #pragma unroll
            for (int j = 0; j < 4; ++j)
                acc[i][j] = __builtin_amdgcn_mfma_f32_16x16x32_bf16(af[i], bfr[j], acc[i][j], 0, 0, 0);
    }

    // epilogue: C/D layout col=lane&15, row=quad*4+r (m89/m91 verified)
    #pragma unroll
    for (int i = 0; i < 4; ++i) {
        #pragma unroll
        for (int j = 0; j < 4; ++j) {
            const int col = bn + wn + j * 16 + l16;
            const float bval = bias[col];
            #pragma unroll
            for (int r = 0; r < 4; ++r) {
                const int row = bm + wm + i * 16 + quad * 4 + r;
                float x = acc[i][j][r] + bval;
                if (EPI == EPI_PHI) x = (x > 0.f) ? (x + 1.f) : __expf(x);  // elu(x)+1
                store_out(C, (size_t)row * N + col, x);
            }
        }
    }
}

// ---------------- b = sigmoid(beta @ Wb^T + bb) : [8192,16], fp32 -------------
__global__ __launch_bounds__(256) void proj_b(const float* __restrict__ beta,
                                              const float* __restrict__ Wb,
                                              const float* __restrict__ bbias,
                                              float* __restrict__ bout)
{
    const int n = threadIdx.x & 15;
    const int mloc = threadIdx.x >> 4;
    const int m = blockIdx.x * 16 + mloc;
    const float4* arow = (const float4*)(beta + (size_t)m * H_DIM);
    const float4* wrow = (const float4*)(Wb + (size_t)n * H_DIM);
    float s = 0.f;
    #pragma unroll 4
    for (int k = 0; k < H_DIM / 4; ++k) {
        float4 a = arow[k], w = wrow[k];
        s = fmaf(a.x, w.x, s); s = fmaf(a.y, w.y, s);
        s = fmaf(a.z, w.z, s); s = fmaf(a.w, w.w, s);
    }
    s += bbias[n];
    bout[(size_t)m * HEADS + n] = 1.f / (1.f + __expf(-s));
}

// ---------------- diagonal delta-rule scan (bf16 in/out, fp32 state) ----------
__global__ __launch_bounds__(64) void scan_kernel(const unsigned short* __restrict__ pk_,
                                                  unsigned short* __restrict__ pq_,   // in: phi_q, out: ys
                                                  const unsigned short* __restrict__ v_,
                                                  const float* __restrict__ b_)
{
    const int bb = blockIdx.x >> 4;
    const int h  = blockIdx.x & 15;
    const int d  = threadIdx.x;
    const size_t base = (size_t)bb * SEQ * H_DIM + h * HD + d;
    const unsigned short* pkp = pk_ + base;
    unsigned short*       pqp = pq_ + base;
    const unsigned short* vp  = v_ + base;
    const float*          bp  = b_ + (size_t)bb * SEQ * HEADS + h;

    float s = 0.f;
    for (int t = 0; t < SEQ; ++t) {
        float pk = bf2f(pkp[(size_t)t * H_DIM]);
        float pq = bf2f(pqp[(size_t)t * H_DIM]);
        float vv = bf2f(vp[(size_t)t * H_DIM]);
        float bt = bp[(size_t)t * HEADS];
        float bdv = bt * (vv - s * pk);   // b*(v - s*pk)
        s = fmaf(bdv, pk, s);             // s += bdv*pk
        pqp[(size_t)t * H_DIM] = f2bf(s * pq);
    }
}

extern "C" void kernel_launch(void* const* d_in, const int* in_sizes, int n_in,
                              void* d_out, int out_size, void* d_ws, size_t ws_size,
                              hipStream_t stream)
{
    const float* query = (const float*)d_in[0];
    const float* key   = (const float*)d_in[1];
    const float* value = (const float*)d_in[2];
    const float* beta  = (const float*)d_in[3];
    const float* Wq    = (const float*)d_in[4];
    const float* bq    = (const float*)d_in[5];
    const float* Wk    = (const float*)d_in[6];
    const float* bk    = (const float*)d_in[7];
    const float* Wv    = (const float*)d_in[8];
    const float* bv    = (const float*)d_in[9];
    const float* Wb    = (const float*)d_in[10];
    const float* bbias = (const float*)d_in[11];
    const float* Wo    = (const float*)d_in[12];
    const float* bo    = (const float*)d_in[13];
    float* out = (float*)d_out;

    const size_t ACT = (size_t)M_ROWS * H_DIM;   // 8 Mi elems
    const size_t WEL = (size_t)H_DIM * H_DIM;    // 1 Mi elems

    unsigned short* ws = (unsigned short*)d_ws;
    unsigned short* Xbf    = ws;                 // staging for cast input (reused serially)
    unsigned short* phi_q  = ws + ACT;           // bf16 [8192,1024]; ys written in-place
    unsigned short* phi_k  = ws + 2 * ACT;
    unsigned short* vbuf   = ws + 3 * ACT;
    unsigned short* Wq_bf  = ws + 4 * ACT;
    unsigned short* Wk_bf  = Wq_bf + WEL;
    unsigned short* Wv_bf  = Wk_bf + WEL;
    unsigned short* Wo_bf  = Wv_bf + WEL;
    float*          bbuf   = (float*)(Wo_bf + WEL);   // fp32 [8192,16]

    const int ACT_CAST_BLOCKS = (int)(ACT / (8 * 256));   // 4096
    const int W_CAST_BLOCKS   = (int)(WEL / (8 * 256));   // 512

    // weight casts (once per launch; cheap)
    cast_bf16<<<W_CAST_BLOCKS, 256, 0, stream>>>(Wq, Wq_bf);
    cast_bf16<<<W_CAST_BLOCKS, 256, 0, stream>>>(Wk, Wk_bf);
    cast_bf16<<<W_CAST_BLOCKS, 256, 0, stream>>>(Wv, Wv_bf);
    cast_bf16<<<W_CAST_BLOCKS, 256, 0, stream>>>(Wo, Wo_bf);

    dim3 ggrid(H_DIM / 128, M_ROWS / 128);   // (8, 64) = 512 blocks

    cast_bf16<<<ACT_CAST_BLOCKS, 256, 0, stream>>>(query, Xbf);
    gemm_mfma<EPI_PHI, unsigned short><<<ggrid, 256, 0, stream>>>(Xbf, Wq_bf, bq, phi_q, M_ROWS, H_DIM, H_DIM);
    cast_bf16<<<ACT_CAST_BLOCKS, 256, 0, stream>>>(key, Xbf);
    gemm_mfma<EPI_PHI, unsigned short><<<ggrid, 256, 0, stream>>>(Xbf, Wk_bf, bk, phi_k, M_ROWS, H_DIM, H_DIM);
    cast_bf16<<<ACT_CAST_BLOCKS, 256, 0, stream>>>(value, Xbf);
    gemm_mfma<EPI_NONE, unsigned short><<<ggrid, 256, 0, stream>>>(Xbf, Wv_bf, bv, vbuf, M_ROWS, H_DIM, H_DIM);

    proj_b<<<M_ROWS / 16, 256, 0, stream>>>(beta, Wb, bbias, bbuf);
    scan_kernel<<<BATCH * HEADS, 64, 0, stream>>>(phi_k, phi_q, vbuf, bbuf);

    gemm_mfma<EPI_NONE, float><<<ggrid, 256, 0, stream>>>(phi_q, Wo_bf, bo, out, M_ROWS, H_DIM, H_DIM);
}

// Round 3
// 549.982 us; speedup vs baseline: 2.3365x; 1.2474x over previous
//
#include <hip/hip_runtime.h>
#include <cstdint>
#include <cstddef>

#define H_DIM 1024
#define HEADS 16
#define HD 64
#define BATCH 4
#define SEQ 2048
#define M_ROWS (BATCH*SEQ)   // 8192

typedef __bf16 bf16x8 __attribute__((ext_vector_type(8)));
typedef float floatx4 __attribute__((ext_vector_type(4)));
typedef unsigned short ushortx8 __attribute__((ext_vector_type(8)));

__device__ __forceinline__ unsigned short f2bf(float f) {
    union { float f; uint32_t u; } c; c.f = f;
    uint32_t u = c.u;
    u += 0x7fffu + ((u >> 16) & 1u);     // RNE
    return (unsigned short)(u >> 16);
}
__device__ __forceinline__ float bf2f(unsigned short h) {
    union { uint32_t u; float f; } c; c.u = ((uint32_t)h) << 16;
    return c.f;
}

// async global->LDS, 16B per lane; LDS dest = wave-uniform base + lane*16 (m104/m108)
#define GLD_LDS16(gp, lp) \
    __builtin_amdgcn_global_load_lds((__attribute__((address_space(1))) void*)(gp), \
                                     (__attribute__((address_space(3))) void*)(lp), 16, 0, 0)

// ---------------- elementwise f32 -> bf16 cast (8 elems/thread) ----------------
__global__ __launch_bounds__(256) void cast_bf16(const float* __restrict__ in,
                                                 unsigned short* __restrict__ out)
{
    size_t i = (size_t)blockIdx.x * 256 + threadIdx.x;
    const float4* p = (const float4*)in;
    float4 a = p[i * 2], b = p[i * 2 + 1];
    ushortx8 o;
    o[0] = f2bf(a.x); o[1] = f2bf(a.y); o[2] = f2bf(a.z); o[3] = f2bf(a.w);
    o[4] = f2bf(b.x); o[5] = f2bf(b.y); o[6] = f2bf(b.z); o[7] = f2bf(b.w);
    *(ushortx8*)(out + i * 8) = o;
}

// ---------------- bf16 MFMA GEMM: C[m,n] = sum_k A[m,k]*W[n,k] + bias[n] ------
// m97 structure: 128x128 tile, BK=32, 4 waves x (4x4) 16x16x32 MFMA tiles.
enum { EPI_NONE = 0, EPI_PHI = 1 };

__device__ __forceinline__ void store_out(float* C, size_t idx, float x) { C[idx] = x; }
__device__ __forceinline__ void store_out(unsigned short* C, size_t idx, float x) { C[idx] = f2bf(x); }

template<int EPI, typename OutT>
__global__ __launch_bounds__(256) void gemm_mfma(const unsigned short* __restrict__ A,  // [M,K] bf16
                                                 const unsigned short* __restrict__ W,  // [N,K] bf16
                                                 const float* __restrict__ bias,
                                                 OutT* __restrict__ C,
                                                 int M, int N, int K)
{
    constexpr int TM = 128, TN = 128, TK = 32;
    __shared__ __align__(16) unsigned short Ast[TM * TK];  // row-major [128][32]
    __shared__ __align__(16) unsigned short Bst[TN * TK];

    const int tid  = threadIdx.x;
    const int wave = tid >> 6;
    const int lane = tid & 63;
    const int bm = blockIdx.y * TM;
    const int bn = blockIdx.x * TN;

    // staging: wave covers 16 rows per issue; lane i -> row i>>2, k-chunk (i&3)*8
    const int srow  = wave * 16 + (lane >> 2);
    const int skoff = (lane & 3) * 8;

    const int wm   = (wave & 1) * 64;   // wave's 64x64 quadrant
    const int wn   = (wave >> 1) * 64;
    const int quad = lane >> 4;
    const int l16  = lane & 15;

    floatx4 acc[4][4] = {};

    const unsigned short* Abase = A + (size_t)bm * K;
    const unsigned short* Wbase = W + (size_t)bn * K;

    for (int k0 = 0; k0 < K; k0 += TK) {
        __syncthreads();  // prior iteration's ds_reads complete before overwrite
        GLD_LDS16(Abase + (size_t)srow        * K + k0 + skoff, &Ast[(wave * 16)      * TK]);
        GLD_LDS16(Abase + (size_t)(srow + 64) * K + k0 + skoff, &Ast[(64 + wave * 16) * TK]);
        GLD_LDS16(Wbase + (size_t)srow        * K + k0 + skoff, &Bst[(wave * 16)      * TK]);
        GLD_LDS16(Wbase + (size_t)(srow + 64) * K + k0 + skoff, &Bst[(64 + wave * 16) * TK]);
        __syncthreads();  // drains vmcnt (staging) + lgkm

        bf16x8 af[4], bfr[4];
        #pragma unroll
        for (int i = 0; i < 4; ++i)
            af[i] = *(const bf16x8*)&Ast[(wm + i * 16 + l16) * TK + quad * 8];
        #pragma unroll
        for (int j = 0; j < 4; ++j)
            bfr[j] = *(const bf16x8*)&Bst[(wn + j * 16 + l16) * TK + quad * 8];
        #pragma unroll
        for (int i = 0; i < 4; ++i)
            #pragma unroll
            for (int j = 0; j < 4; ++j)
                acc[i][j] = __builtin_amdgcn_mfma_f32_16x16x32_bf16(af[i], bfr[j], acc[i][j], 0, 0, 0);
    }

    // epilogue: C/D layout col=lane&15, row=quad*4+r (m89/m91 verified)
    #pragma unroll
    for (int i = 0; i < 4; ++i) {
        #pragma unroll
        for (int j = 0; j < 4; ++j) {
            const int col = bn + wn + j * 16 + l16;
            const float bval = bias[col];
            #pragma unroll
            for (int r = 0; r < 4; ++r) {
                const int row = bm + wm + i * 16 + quad * 4 + r;
                float x = acc[i][j][r] + bval;
                if (EPI == EPI_PHI) x = (x > 0.f) ? (x + 1.f) : __expf(x);  // elu(x)+1
                store_out(C, (size_t)row * N + col, x);
            }
        }
    }
}

// ---------------- b = sigmoid(beta @ Wb^T + bb) : [8192,16], fp32 -------------
__global__ __launch_bounds__(256) void proj_b(const float* __restrict__ beta,
                                              const float* __restrict__ Wb,
                                              const float* __restrict__ bbias,
                                              float* __restrict__ bout)
{
    const int n = threadIdx.x & 15;
    const int mloc = threadIdx.x >> 4;
    const int m = blockIdx.x * 16 + mloc;
    const float4* arow = (const float4*)(beta + (size_t)m * H_DIM);
    const float4* wrow = (const float4*)(Wb + (size_t)n * H_DIM);
    float s = 0.f;
    #pragma unroll 4
    for (int k = 0; k < H_DIM / 4; ++k) {
        float4 a = arow[k], w = wrow[k];
        s = fmaf(a.x, w.x, s); s = fmaf(a.y, w.y, s);
        s = fmaf(a.z, w.z, s); s = fmaf(a.w, w.w, s);
    }
    s += bbias[n];
    bout[(size_t)m * HEADS + n] = 1.f / (1.f + __expf(-s));
}

// ---------------- diagonal delta-rule scan (bf16 in/out, fp32 state) ----------
// Depth-PF register-ring software pipeline: loads are state-independent, so we
// keep PF iterations of (pk,pq,v,b) in flight ahead of the serial chain.
__global__ __launch_bounds__(64) void scan_kernel(const unsigned short* __restrict__ pk_,
                                                  unsigned short* __restrict__ pq_,   // in: phi_q, out: ys
                                                  const unsigned short* __restrict__ v_,
                                                  const float* __restrict__ b_)
{
    constexpr int PF = 16;
    const int bb = blockIdx.x >> 4;
    const int h  = blockIdx.x & 15;
    const int d  = threadIdx.x;
    const size_t base = (size_t)bb * SEQ * H_DIM + h * HD + d;
    const unsigned short* pkp = pk_ + base;
    unsigned short*       pqp = pq_ + base;
    const unsigned short* vp  = v_ + base;
    const float*          bp  = b_ + (size_t)bb * SEQ * HEADS + h;

    unsigned short pkb[PF], pqb[PF], vvb[PF];
    float btb[PF];
    #pragma unroll
    for (int i = 0; i < PF; ++i) {
        pkb[i] = pkp[(size_t)i * H_DIM];
        pqb[i] = pqp[(size_t)i * H_DIM];
        vvb[i] = vp[(size_t)i * H_DIM];
        btb[i] = bp[(size_t)i * HEADS];
    }

    float s = 0.f;
    for (int t0 = 0; t0 < SEQ; t0 += PF) {
        #pragma unroll
        for (int i = 0; i < PF; ++i) {
            const int t = t0 + i;
            // consume slot i
            float pk = bf2f(pkb[i]);
            float pq = bf2f(pqb[i]);
            float vv = bf2f(vvb[i]);
            float bt = btb[i];
            // refill slot i with t+PF (mask to stay in-bounds; wrapped values unused)
            const int tp = (t + PF) & (SEQ - 1);
            pkb[i] = pkp[(size_t)tp * H_DIM];
            pqb[i] = pqp[(size_t)tp * H_DIM];
            vvb[i] = vp[(size_t)tp * H_DIM];
            btb[i] = bp[(size_t)tp * HEADS];
            // serial chain
            float bdv = bt * (vv - s * pk);   // b*(v - s*pk)
            s = fmaf(bdv, pk, s);             // s += bdv*pk
            pqp[(size_t)t * H_DIM] = f2bf(s * pq);
        }
    }
}

extern "C" void kernel_launch(void* const* d_in, const int* in_sizes, int n_in,
                              void* d_out, int out_size, void* d_ws, size_t ws_size,
                              hipStream_t stream)
{
    const float* query = (const float*)d_in[0];
    const float* key   = (const float*)d_in[1];
    const float* value = (const float*)d_in[2];
    const float* beta  = (const float*)d_in[3];
    const float* Wq    = (const float*)d_in[4];
    const float* bq    = (const float*)d_in[5];
    const float* Wk    = (const float*)d_in[6];
    const float* bk    = (const float*)d_in[7];
    const float* Wv    = (const float*)d_in[8];
    const float* bv    = (const float*)d_in[9];
    const float* Wb    = (const float*)d_in[10];
    const float* bbias = (const float*)d_in[11];
    const float* Wo    = (const float*)d_in[12];
    const float* bo    = (const float*)d_in[13];
    float* out = (float*)d_out;

    const size_t ACT = (size_t)M_ROWS * H_DIM;   // 8 Mi elems
    const size_t WEL = (size_t)H_DIM * H_DIM;    // 1 Mi elems

    unsigned short* ws = (unsigned short*)d_ws;
    unsigned short* Xbf    = ws;                 // staging for cast input (reused serially)
    unsigned short* phi_q  = ws + ACT;           // bf16 [8192,1024]; ys written in-place
    unsigned short* phi_k  = ws + 2 * ACT;
    unsigned short* vbuf   = ws + 3 * ACT;
    unsigned short* Wq_bf  = ws + 4 * ACT;
    unsigned short* Wk_bf  = Wq_bf + WEL;
    unsigned short* Wv_bf  = Wk_bf + WEL;
    unsigned short* Wo_bf  = Wv_bf + WEL;
    float*          bbuf   = (float*)(Wo_bf + WEL);   // fp32 [8192,16]

    const int ACT_CAST_BLOCKS = (int)(ACT / (8 * 256));   // 4096
    const int W_CAST_BLOCKS   = (int)(WEL / (8 * 256));   // 512

    // weight casts (once per launch; cheap)
    cast_bf16<<<W_CAST_BLOCKS, 256, 0, stream>>>(Wq, Wq_bf);
    cast_bf16<<<W_CAST_BLOCKS, 256, 0, stream>>>(Wk, Wk_bf);
    cast_bf16<<<W_CAST_BLOCKS, 256, 0, stream>>>(Wv, Wv_bf);
    cast_bf16<<<W_CAST_BLOCKS, 256, 0, stream>>>(Wo, Wo_bf);

    dim3 ggrid(H_DIM / 128, M_ROWS / 128);   // (8, 64) = 512 blocks

    cast_bf16<<<ACT_CAST_BLOCKS, 256, 0, stream>>>(query, Xbf);
    gemm_mfma<EPI_PHI, unsigned short><<<ggrid, 256, 0, stream>>>(Xbf, Wq_bf, bq, phi_q, M_ROWS, H_DIM, H_DIM);
    cast_bf16<<<ACT_CAST_BLOCKS, 256, 0, stream>>>(key, Xbf);
    gemm_mfma<EPI_PHI, unsigned short><<<ggrid, 256, 0, stream>>>(Xbf, Wk_bf, bk, phi_k, M_ROWS, H_DIM, H_DIM);
    cast_bf16<<<ACT_CAST_BLOCKS, 256, 0, stream>>>(value, Xbf);
    gemm_mfma<EPI_NONE, unsigned short><<<ggrid, 256, 0, stream>>>(Xbf, Wv_bf, bv, vbuf, M_ROWS, H_DIM, H_DIM);

    proj_b<<<M_ROWS / 16, 256, 0, stream>>>(beta, Wb, bbias, bbuf);
    scan_kernel<<<BATCH * HEADS, 64, 0, stream>>>(phi_k, phi_q, vbuf, bbuf);

    gemm_mfma<EPI_NONE, float><<<ggrid, 256, 0, stream>>>(phi_q, Wo_bf, bo, out, M_ROWS, H_DIM, H_DIM);
}

// Round 4
// 426.261 us; speedup vs baseline: 3.0146x; 1.2902x over previous
//
#include <hip/hip_runtime.h>
#include <cstdint>
#include <cstddef>

#define H_DIM 1024
#define HEADS 16
#define HD 64
#define BATCH 4
#define SEQ 2048
#define M_ROWS (BATCH*SEQ)   // 8192

typedef __bf16 bf16x8 __attribute__((ext_vector_type(8)));
typedef float floatx4 __attribute__((ext_vector_type(4)));
typedef unsigned short ushortx8 __attribute__((ext_vector_type(8)));

__device__ __forceinline__ unsigned short f2bf(float f) {
    union { float f; uint32_t u; } c; c.f = f;
    uint32_t u = c.u;
    u += 0x7fffu + ((u >> 16) & 1u);     // RNE
    return (unsigned short)(u >> 16);
}
__device__ __forceinline__ float bf2f(unsigned short h) {
    union { uint32_t u; float f; } c; c.u = ((uint32_t)h) << 16;
    return c.f;
}

// async global->LDS, 16B per lane; LDS dest = wave-uniform base + lane*16 (m104/m108)
#define GLD_LDS16(gp, lp) \
    __builtin_amdgcn_global_load_lds((__attribute__((address_space(1))) void*)(gp), \
                                     (__attribute__((address_space(3))) void*)(lp), 16, 0, 0)

// ---------------- elementwise f32 -> bf16 cast (8 elems/thread) ----------------
__global__ __launch_bounds__(256) void cast_bf16(const float* __restrict__ in,
                                                 unsigned short* __restrict__ out)
{
    size_t i = (size_t)blockIdx.x * 256 + threadIdx.x;
    const float4* p = (const float4*)in;
    float4 a = p[i * 2], b = p[i * 2 + 1];
    ushortx8 o;
    o[0] = f2bf(a.x); o[1] = f2bf(a.y); o[2] = f2bf(a.z); o[3] = f2bf(a.w);
    o[4] = f2bf(b.x); o[5] = f2bf(b.y); o[6] = f2bf(b.z); o[7] = f2bf(b.w);
    *(ushortx8*)(out + i * 8) = o;
}

// ---------------- bf16 MFMA GEMM: C[m,n] = sum_k A[m,k]*W[n,k] + bias[n] ------
enum { EPI_NONE = 0, EPI_PHI = 1 };

__device__ __forceinline__ void store_out(float* C, size_t idx, float x) { C[idx] = x; }
__device__ __forceinline__ void store_out(unsigned short* C, size_t idx, float x) { C[idx] = f2bf(x); }

template<int EPI, typename OutT>
__global__ __launch_bounds__(256) void gemm_mfma(const unsigned short* __restrict__ A,  // [M,K] bf16
                                                 const unsigned short* __restrict__ W,  // [N,K] bf16
                                                 const float* __restrict__ bias,
                                                 OutT* __restrict__ C,
                                                 int M, int N, int K)
{
    constexpr int TM = 128, TN = 128, TK = 32;
    __shared__ __align__(16) unsigned short Ast[TM * TK];
    __shared__ __align__(16) unsigned short Bst[TN * TK];

    const int tid  = threadIdx.x;
    const int wave = tid >> 6;
    const int lane = tid & 63;
    const int bm = blockIdx.y * TM;
    const int bn = blockIdx.x * TN;

    const int srow  = wave * 16 + (lane >> 2);
    const int skoff = (lane & 3) * 8;

    const int wm   = (wave & 1) * 64;
    const int wn   = (wave >> 1) * 64;
    const int quad = lane >> 4;
    const int l16  = lane & 15;

    floatx4 acc[4][4] = {};

    const unsigned short* Abase = A + (size_t)bm * K;
    const unsigned short* Wbase = W + (size_t)bn * K;

    for (int k0 = 0; k0 < K; k0 += TK) {
        __syncthreads();
        GLD_LDS16(Abase + (size_t)srow        * K + k0 + skoff, &Ast[(wave * 16)      * TK]);
        GLD_LDS16(Abase + (size_t)(srow + 64) * K + k0 + skoff, &Ast[(64 + wave * 16) * TK]);
        GLD_LDS16(Wbase + (size_t)srow        * K + k0 + skoff, &Bst[(wave * 16)      * TK]);
        GLD_LDS16(Wbase + (size_t)(srow + 64) * K + k0 + skoff, &Bst[(64 + wave * 16) * TK]);
        __syncthreads();

        bf16x8 af[4], bfr[4];
        #pragma unroll
        for (int i = 0; i < 4; ++i)
            af[i] = *(const bf16x8*)&Ast[(wm + i * 16 + l16) * TK + quad * 8];
        #pragma unroll
        for (int j = 0; j < 4; ++j)
            bfr[j] = *(const bf16x8*)&Bst[(wn + j * 16 + l16) * TK + quad * 8];
        #pragma unroll
        for (int i = 0; i < 4; ++i)
            #pragma unroll
            for (int j = 0; j < 4; ++j)
                acc[i][j] = __builtin_amdgcn_mfma_f32_16x16x32_bf16(af[i], bfr[j], acc[i][j], 0, 0, 0);
    }

    #pragma unroll
    for (int i = 0; i < 4; ++i) {
        #pragma unroll
        for (int j = 0; j < 4; ++j) {
            const int col = bn + wn + j * 16 + l16;
            const float bval = bias[col];
            #pragma unroll
            for (int r = 0; r < 4; ++r) {
                const int row = bm + wm + i * 16 + quad * 4 + r;
                float x = acc[i][j][r] + bval;
                if (EPI == EPI_PHI) x = (x > 0.f) ? (x + 1.f) : __expf(x);  // elu(x)+1
                store_out(C, (size_t)row * N + col, x);
            }
        }
    }
}

// ---------------- b = sigmoid(beta @ Wb^T + bb) : [8192,16], fp32 -------------
__global__ __launch_bounds__(256) void proj_b(const float* __restrict__ beta,
                                              const float* __restrict__ Wb,
                                              const float* __restrict__ bbias,
                                              float* __restrict__ bout)
{
    const int n = threadIdx.x & 15;
    const int mloc = threadIdx.x >> 4;
    const int m = blockIdx.x * 16 + mloc;
    const float4* arow = (const float4*)(beta + (size_t)m * H_DIM);
    const float4* wrow = (const float4*)(Wb + (size_t)n * H_DIM);
    float s = 0.f;
    #pragma unroll 4
    for (int k = 0; k < H_DIM / 4; ++k) {
        float4 a = arow[k], w = wrow[k];
        s = fmaf(a.x, w.x, s); s = fmaf(a.y, w.y, s);
        s = fmaf(a.z, w.z, s); s = fmaf(a.w, w.w, s);
    }
    s += bbias[n];
    bout[(size_t)m * HEADS + n] = 1.f / (1.f + __expf(-s));
}

// ---------------- chunked parallel linear scan -------------------------------
// s_t = a_t*s_{t-1} + c_t with a = 1 - b*pk^2, c = b*v*pk.
// 64 chunks of 32 steps -> 4096 waves of chunk work (16 waves/CU).
constexpr int NCHUNK = 64;
constexpr int CLEN   = SEQ / NCHUNK;     // 32
constexpr int NGH    = BATCH * HEADS * HD;  // 4096 independent lanes

// Phase 1: per-chunk composition (A = prod a, C = sum c*prod-later-a)
__global__ __launch_bounds__(256) void scan_phase1(const unsigned short* __restrict__ pk_,
                                                   const unsigned short* __restrict__ v_,
                                                   const float* __restrict__ b_,
                                                   float* __restrict__ Aarr,
                                                   float* __restrict__ Carr)
{
    const int idx   = blockIdx.x * 256 + threadIdx.x;   // 0 .. NGH*NCHUNK-1
    const int d     = idx & 63;
    const int h     = (idx >> 6) & 15;
    const int bb    = (idx >> 10) & 3;
    const int chunk = idx >> 12;
    const int g     = idx & (NGH - 1);
    const int t0    = chunk * CLEN;

    const unsigned short* pkp = pk_ + (size_t)bb * SEQ * H_DIM + h * HD + d + (size_t)t0 * H_DIM;
    const unsigned short* vp  = v_  + (size_t)bb * SEQ * H_DIM + h * HD + d + (size_t)t0 * H_DIM;
    const float*          bp  = b_  + (size_t)bb * SEQ * HEADS + h        + (size_t)t0 * HEADS;

    float A = 1.f, C = 0.f;
    #pragma unroll 8
    for (int t = 0; t < CLEN; ++t) {
        float pk = bf2f(pkp[(size_t)t * H_DIM]);
        float vv = bf2f(vp[(size_t)t * H_DIM]);
        float bt = bp[(size_t)t * HEADS];
        float a  = 1.f - bt * pk * pk;
        float c  = bt * vv * pk;
        A *= a;
        C = fmaf(a, C, c);
    }
    Aarr[(size_t)chunk * NGH + g] = A;
    Carr[(size_t)chunk * NGH + g] = C;
}

// Phase 2: serial scan over the 64 chunk summaries -> chunk-start states
__global__ __launch_bounds__(256) void scan_phase2(const float* __restrict__ Aarr,
                                                   const float* __restrict__ Carr,
                                                   float* __restrict__ S0)
{
    const int g = blockIdx.x * 256 + threadIdx.x;   // 0..4095
    float s = 0.f;
    #pragma unroll
    for (int c = 0; c < NCHUNK; ++c) {
        S0[(size_t)c * NGH + g] = s;
        s = fmaf(Aarr[(size_t)c * NGH + g], s, Carr[(size_t)c * NGH + g]);
    }
}

// Phase 3: replay original recurrence within each chunk from S0, write y
__global__ __launch_bounds__(256) void scan_phase3(const unsigned short* __restrict__ pk_,
                                                   unsigned short* __restrict__ pq_,   // in: phi_q, out: ys
                                                   const unsigned short* __restrict__ v_,
                                                   const float* __restrict__ b_,
                                                   const float* __restrict__ S0)
{
    const int idx   = blockIdx.x * 256 + threadIdx.x;
    const int d     = idx & 63;
    const int h     = (idx >> 6) & 15;
    const int bb    = (idx >> 10) & 3;
    const int chunk = idx >> 12;
    const int g     = idx & (NGH - 1);
    const int t0    = chunk * CLEN;

    const unsigned short* pkp = pk_ + (size_t)bb * SEQ * H_DIM + h * HD + d + (size_t)t0 * H_DIM;
    unsigned short*       pqp = pq_ + (size_t)bb * SEQ * H_DIM + h * HD + d + (size_t)t0 * H_DIM;
    const unsigned short* vp  = v_  + (size_t)bb * SEQ * H_DIM + h * HD + d + (size_t)t0 * H_DIM;
    const float*          bp  = b_  + (size_t)bb * SEQ * HEADS + h        + (size_t)t0 * HEADS;

    float s = S0[(size_t)chunk * NGH + g];
    #pragma unroll 8
    for (int t = 0; t < CLEN; ++t) {
        float pk = bf2f(pkp[(size_t)t * H_DIM]);
        float pq = bf2f(pqp[(size_t)t * H_DIM]);
        float vv = bf2f(vp[(size_t)t * H_DIM]);
        float bt = bp[(size_t)t * HEADS];
        float bdv = bt * (vv - s * pk);   // identical op order to the sequential version
        s = fmaf(bdv, pk, s);
        pqp[(size_t)t * H_DIM] = f2bf(s * pq);
    }
}

extern "C" void kernel_launch(void* const* d_in, const int* in_sizes, int n_in,
                              void* d_out, int out_size, void* d_ws, size_t ws_size,
                              hipStream_t stream)
{
    const float* query = (const float*)d_in[0];
    const float* key   = (const float*)d_in[1];
    const float* value = (const float*)d_in[2];
    const float* beta  = (const float*)d_in[3];
    const float* Wq    = (const float*)d_in[4];
    const float* bq    = (const float*)d_in[5];
    const float* Wk    = (const float*)d_in[6];
    const float* bk    = (const float*)d_in[7];
    const float* Wv    = (const float*)d_in[8];
    const float* bv    = (const float*)d_in[9];
    const float* Wb    = (const float*)d_in[10];
    const float* bbias = (const float*)d_in[11];
    const float* Wo    = (const float*)d_in[12];
    const float* bo    = (const float*)d_in[13];
    float* out = (float*)d_out;

    const size_t ACT = (size_t)M_ROWS * H_DIM;   // 8 Mi elems
    const size_t WEL = (size_t)H_DIM * H_DIM;    // 1 Mi elems

    unsigned short* ws = (unsigned short*)d_ws;
    unsigned short* Xbf    = ws;                 // staging for cast input (reused serially)
    unsigned short* phi_q  = ws + ACT;           // bf16 [8192,1024]; ys written in-place
    unsigned short* phi_k  = ws + 2 * ACT;
    unsigned short* vbuf   = ws + 3 * ACT;
    unsigned short* Wq_bf  = ws + 4 * ACT;
    unsigned short* Wk_bf  = Wq_bf + WEL;
    unsigned short* Wv_bf  = Wk_bf + WEL;
    unsigned short* Wo_bf  = Wv_bf + WEL;
    float*          bbuf   = (float*)(Wo_bf + WEL);        // [8192,16]
    float*          Aarr   = bbuf + (size_t)M_ROWS * HEADS; // [64][4096]
    float*          Carr   = Aarr + (size_t)NCHUNK * NGH;
    float*          S0     = Carr + (size_t)NCHUNK * NGH;

    const int ACT_CAST_BLOCKS = (int)(ACT / (8 * 256));   // 4096
    const int W_CAST_BLOCKS   = (int)(WEL / (8 * 256));   // 512

    cast_bf16<<<W_CAST_BLOCKS, 256, 0, stream>>>(Wq, Wq_bf);
    cast_bf16<<<W_CAST_BLOCKS, 256, 0, stream>>>(Wk, Wk_bf);
    cast_bf16<<<W_CAST_BLOCKS, 256, 0, stream>>>(Wv, Wv_bf);
    cast_bf16<<<W_CAST_BLOCKS, 256, 0, stream>>>(Wo, Wo_bf);

    dim3 ggrid(H_DIM / 128, M_ROWS / 128);   // (8, 64) = 512 blocks

    cast_bf16<<<ACT_CAST_BLOCKS, 256, 0, stream>>>(query, Xbf);
    gemm_mfma<EPI_PHI, unsigned short><<<ggrid, 256, 0, stream>>>(Xbf, Wq_bf, bq, phi_q, M_ROWS, H_DIM, H_DIM);
    cast_bf16<<<ACT_CAST_BLOCKS, 256, 0, stream>>>(key, Xbf);
    gemm_mfma<EPI_PHI, unsigned short><<<ggrid, 256, 0, stream>>>(Xbf, Wk_bf, bk, phi_k, M_ROWS, H_DIM, H_DIM);
    cast_bf16<<<ACT_CAST_BLOCKS, 256, 0, stream>>>(value, Xbf);
    gemm_mfma<EPI_NONE, unsigned short><<<ggrid, 256, 0, stream>>>(Xbf, Wv_bf, bv, vbuf, M_ROWS, H_DIM, H_DIM);

    proj_b<<<M_ROWS / 16, 256, 0, stream>>>(beta, Wb, bbias, bbuf);

    const int SCAN_BLOCKS = NGH * NCHUNK / 256;   // 1024
    scan_phase1<<<SCAN_BLOCKS, 256, 0, stream>>>(phi_k, vbuf, bbuf, Aarr, Carr);
    scan_phase2<<<NGH / 256, 256, 0, stream>>>(Aarr, Carr, S0);
    scan_phase3<<<SCAN_BLOCKS, 256, 0, stream>>>(phi_k, phi_q, vbuf, bbuf, S0);

    gemm_mfma<EPI_NONE, float><<<ggrid, 256, 0, stream>>>(phi_q, Wo_bf, bo, out, M_ROWS, H_DIM, H_DIM);
}